// Round 5
// baseline (530.469 us; speedup 1.0000x reference)
//
#include <hip/hip_runtime.h>

#define NB 256
#define NT 512
#define NI 64
#define NH 256
#define NO 16

typedef __attribute__((ext_vector_type(8))) short short8;
typedef __attribute__((ext_vector_type(8))) __bf16 bf16x8;
typedef __attribute__((ext_vector_type(4))) float f32x4;
typedef __attribute__((ext_vector_type(2))) unsigned int uint2v;

__device__ __forceinline__ unsigned short f2bf(float f) {
  unsigned u = __builtin_bit_cast(unsigned, f);
  u += 0x7fffu + ((u >> 16) & 1u);          // round-to-nearest-even
  return (unsigned short)(u >> 16);
}

// D = A*B + C ; A = weights [16m x 32k] (VGPR), B = activations [32k x 16n]
__device__ __forceinline__ f32x4 mfma16(short8 a, short8 b, f32x4 c) {
  return __builtin_amdgcn_mfma_f32_16x16x32_bf16(
      __builtin_bit_cast(bf16x8, a), __builtin_bit_cast(bf16x8, b), c, 0, 0, 0);
}

__device__ __forceinline__ short8 pack8v(f32x4 lo, f32x4 hi) {
  short8 r;
#pragma unroll
  for (int i = 0; i < 4; ++i) {
    r[i]     = (short)f2bf(lo[i]);
    r[i + 4] = (short)f2bf(hi[i]);
  }
  return r;
}

__device__ __forceinline__ short8 pack8(const float* __restrict__ p) {
  return pack8v(*reinterpret_cast<const f32x4*>(p),
                *reinterpret_cast<const f32x4*>(p + 4));
}

__device__ __forceinline__ uint2v packbf4(f32x4 v) {
  uint2v d;
  d.x = (unsigned)f2bf(v[0]) | ((unsigned)f2bf(v[1]) << 16);
  d.y = (unsigned)f2bf(v[2]) | ((unsigned)f2bf(v[3]) << 16);
  return d;
}

// LDS-only barrier: drain DS ops, sync; global loads/stores stay in flight.
__device__ __forceinline__ void step_barrier() {
  asm volatile("s_waitcnt lgkmcnt(0)" ::: "memory");
  __builtin_amdgcn_s_barrier();
  asm volatile("" ::: "memory");
}

// One block per batch (256 blocks -> 1/CU). 256 threads = 4 waves, 1/SIMD.
// Activation vector (h_t ++ x_t, K=320) lives in LDS as MFMA B-fragment
// CHUNKS: frag[buf][kt][kg][e] bf16, k = kt*32 + kg*8 + e. A wave reads frag
// kt with ONE broadcast ds_read_b128 (group kg reads chunk kg). 640B/buffer.
// Wave w owns output rows j in [w*64, w*64+64) (4 m-tiles); only lanes with
// c = l&15 == 0 hold valid MFMA outputs (col 0), h+bias folded into C-in.
__global__ __launch_bounds__(256, 1)
void rnn_fused(const float* __restrict__ x,  const float* __restrict__ Wi,
               const float* __restrict__ bi, const float* __restrict__ Wh,
               const float* __restrict__ bh, const float* __restrict__ Wo,
               const float* __restrict__ bo, const float* __restrict__ h0,
               float* __restrict__ dout)
{
  const int b   = blockIdx.x;
  const int tid = threadIdx.x;
  const int w   = tid >> 6;   // wave 0..3
  const int l   = tid & 63;   // lane
  const int g   = l >> 4;     // 16-lane group = k-chunk index
  const int c   = l & 15;     // col within tile (c==0 -> valid output lane)

  __shared__ __align__(16) unsigned short frag[2][10][4][8];  // 1.25 KB total

  float* outp = dout;                              // [B,T,O]
  float* hidp = dout + (size_t)NB * NT * NO;       // [B,H]
  float* rnnp = hidp + (size_t)NB * NH;            // [B,T,H]

  const f32x4 cz = {0.f, 0.f, 0.f, 0.f};

  // ---- weight A-fragments in VGPRs: lane holds row m=c, k = kt*32+g*8+e ----
  short8 whA[4][10];
#pragma unroll
  for (int mt = 0; mt < 4; ++mt) {
    const int jA = w * 64 + mt * 16 + c;
#pragma unroll
    for (int kt = 0; kt < 8; ++kt)
      whA[mt][kt] = pack8(Wh + (size_t)jA * NH + kt * 32 + g * 8);
#pragma unroll
    for (int kx = 0; kx < 2; ++kx)
      whA[mt][8 + kx] = pack8(Wi + (size_t)jA * NI + kx * 32 + g * 8);
  }
  short8 woA[8];
#pragma unroll
  for (int kt = 0; kt < 8; ++kt)
    woA[kt] = pack8(Wo + (size_t)c * NH + kt * 32 + g * 8);

  f32x4 biasv[4], aprev[4], obias;
#pragma unroll
  for (int mt = 0; mt < 4; ++mt) {
#pragma unroll
    for (int r = 0; r < 4; ++r) {
      const int jD = w * 64 + mt * 16 + 4 * g + r;
      biasv[mt][r] = bi[jD] + bh[jD];
      aprev[mt][r] = h0[jD];
    }
  }
#pragma unroll
  for (int r = 0; r < 4; ++r) obias[r] = bo[4 * g + r];

  // ---- x prefetch, 2 windows deep: lane c holds x[t0+c][g*8..], [32+g*8..]
  const float* xbase = x + (size_t)b * NT * NI + (size_t)c * NI + g * 8;
  f32x4 xA[4], xB[4];
  xA[0] = *reinterpret_cast<const f32x4*>(xbase);
  xA[1] = *reinterpret_cast<const f32x4*>(xbase + 4);
  xA[2] = *reinterpret_cast<const f32x4*>(xbase + 32);
  xA[3] = *reinterpret_cast<const f32x4*>(xbase + 36);
  xB[0] = *reinterpret_cast<const f32x4*>(xbase + 16 * NI);
  xB[1] = *reinterpret_cast<const f32x4*>(xbase + 16 * NI + 4);
  xB[2] = *reinterpret_cast<const f32x4*>(xbase + 16 * NI + 32);
  xB[3] = *reinterpret_cast<const f32x4*>(xbase + 16 * NI + 36);

  // ---- init buf0: h0 chunks (thread j writes h0[j]) + x0 chunks ----
  {
    const int j = tid;
    frag[0][j >> 5][(j >> 3) & 3][j & 7] = f2bf(h0[j]);
  }
  if (w == 0 && c == 0) {   // lane c==0 holds x[0]
    *(short8*)&frag[0][8][g][0] = pack8v(xA[0], xA[1]);
    *(short8*)&frag[0][9][g][0] = pack8v(xA[2], xA[3]);
  }
  __syncthreads();

  auto STEP = [&](int t, int p) {
    // ---- 10 broadcast b128 reads: full K=320 B-operand, 640 bytes ----
    short8 bfr[10];
#pragma unroll
    for (int kt = 0; kt < 10; ++kt)
      bfr[kt] = *(const short8*)&frag[p][kt][g][0];

    // ---- h2h+i2h: 8 independent 5-deep chains; h+bias in C-in (col 0) ----
    f32x4 accA[4], accB[4];
#pragma unroll
    for (int mt = 0; mt < 4; ++mt)
      accA[mt] = mfma16(whA[mt][0], bfr[0], aprev[mt] + biasv[mt]);
#pragma unroll
    for (int mt = 0; mt < 4; ++mt)
      accB[mt] = mfma16(whA[mt][5], bfr[5], cz);
#pragma unroll
    for (int kk = 1; kk < 5; ++kk) {
#pragma unroll
      for (int mt = 0; mt < 4; ++mt) {
        accA[mt] = mfma16(whA[mt][kk],     bfr[kk],     accA[mt]);
        accB[mt] = mfma16(whA[mt][5 + kk], bfr[5 + kk], accB[mt]);
      }
    }

    // ---- lagged output projection out[t-1] = Wo·a_{t-1}, rotating wave ----
    if (t > 0 && w == ((t - 1) & 3)) {
      f32x4 oA = mfma16(woA[0], bfr[0], cz);
      f32x4 oB = mfma16(woA[4], bfr[4], cz);
#pragma unroll
      for (int kk = 1; kk < 4; ++kk) {
        oA = mfma16(woA[kk],     bfr[kk],     oA);
        oB = mfma16(woA[4 + kk], bfr[4 + kk], oB);
      }
      if (c == 0) {
        f32x4 o = oA + oB + obias;
        *(f32x4*)(outp + ((size_t)b * NT + (t - 1)) * NO + 4 * g) = o;
      }
    }

    // ---- stage x_{t+1} into buf p^1 (the 4 lanes of wave0 holding it) ----
    {
      const int nr = (t + 1) & 15;
      if (w == 0 && c == nr) {
        if (nr == 0) {  // next window's first step comes from xB
          *(short8*)&frag[p ^ 1][8][g][0] = pack8v(xB[0], xB[1]);
          *(short8*)&frag[p ^ 1][9][g][0] = pack8v(xB[2], xB[3]);
        } else {
          *(short8*)&frag[p ^ 1][8][g][0] = pack8v(xA[0], xA[1]);
          *(short8*)&frag[p ^ 1][9][g][0] = pack8v(xA[2], xA[3]);
        }
      }
    }

    // ---- activation; h-chunk writes + rnn_out store (valid lanes only) ----
#pragma unroll
    for (int mt = 0; mt < 4; ++mt) {
      f32x4 pre = accA[mt] + accB[mt];
      f32x4 a4;
#pragma unroll
      for (int r = 0; r < 4; ++r) a4[r] = fminf(fmaxf(pre[r], 0.f), 1.f);
      aprev[mt] = a4;
    }
    if (c == 0) {
#pragma unroll
      for (int mt = 0; mt < 4; ++mt) {
        const int j0 = w * 64 + mt * 16 + 4 * g;
        *(f32x4*)(rnnp + ((size_t)b * NT + t) * NH + j0) = aprev[mt];
        *(uint2v*)((char*)&frag[p ^ 1][0][0][0] + (j0 >> 5) * 64 +
                   ((j0 >> 3) & 3) * 16 + (j0 & 7) * 2) = packbf4(aprev[mt]);
      }
    }
    step_barrier();
  };

#pragma unroll 1
  for (int t0 = 0; t0 < NT; t0 += 16) {
    if (t0 > 0) {
      // rotate x windows; issue next-next window loads (consumed 15 steps on)
#pragma unroll
      for (int i = 0; i < 4; ++i) xA[i] = xB[i];
      int tl = t0 + 16 + c;
      if (tl > NT - 1) tl = NT - 1;
      const float* xp = x + (size_t)b * NT * NI + (size_t)tl * NI + g * 8;
      xB[0] = *reinterpret_cast<const f32x4*>(xp);
      xB[1] = *reinterpret_cast<const f32x4*>(xp + 4);
      xB[2] = *reinterpret_cast<const f32x4*>(xp + 32);
      xB[3] = *reinterpret_cast<const f32x4*>(xp + 36);
    }
#pragma unroll 1
    for (int tt = 0; tt < 16; tt += 2) {
      STEP(t0 + tt,     0);
      STEP(t0 + tt + 1, 1);
    }
  }

  // ---- epilogue: out[511] from buf0 (holds a_511 chunks); hidden ----
  if (w == 0) {
    short8 bfr[8];
#pragma unroll
    for (int kt = 0; kt < 8; ++kt)
      bfr[kt] = *(const short8*)&frag[0][kt][g][0];
    f32x4 oA = mfma16(woA[0], bfr[0], cz);
    f32x4 oB = mfma16(woA[4], bfr[4], cz);
#pragma unroll
    for (int kk = 1; kk < 4; ++kk) {
      oA = mfma16(woA[kk],     bfr[kk],     oA);
      oB = mfma16(woA[4 + kk], bfr[4 + kk], oB);
    }
    if (c == 0) {
      f32x4 o = oA + oB + obias;
      *(f32x4*)(outp + ((size_t)b * NT + (NT - 1)) * NO + 4 * g) = o;
    }
  }
  if (c == 0) {
#pragma unroll
    for (int mt = 0; mt < 4; ++mt) {
      const int j0 = w * 64 + mt * 16 + 4 * g;
      *(f32x4*)(hidp + (size_t)b * NH + j0) = aprev[mt];
    }
  }
}

extern "C" void kernel_launch(void* const* d_in, const int* in_sizes, int n_in,
                              void* d_out, int out_size, void* d_ws, size_t ws_size,
                              hipStream_t stream) {
  const float* x  = (const float*)d_in[0];
  const float* Wi = (const float*)d_in[1];
  const float* bi = (const float*)d_in[2];
  const float* Wh = (const float*)d_in[3];
  const float* bh = (const float*)d_in[4];
  const float* Wo = (const float*)d_in[5];
  const float* bo = (const float*)d_in[6];
  const float* h0 = (const float*)d_in[7];
  rnn_fused<<<dim3(NB), dim3(256), 0, stream>>>(x, Wi, bi, Wh, bh, Wo, bo, h0,
                                                (float*)d_out);
}

// Round 6
// 169.798 us; speedup vs baseline: 3.1241x; 3.1241x over previous
//
#include <hip/hip_runtime.h>

#define NB 256
#define NT 512
#define NI 64
#define NH 256
#define NO 16

typedef __attribute__((ext_vector_type(8))) short short8;
typedef __attribute__((ext_vector_type(8))) __bf16 bf16x8;
typedef __attribute__((ext_vector_type(4))) float f32x4;
typedef __attribute__((ext_vector_type(4))) int int4v;

__device__ __forceinline__ unsigned short f2bf(float f) {
  unsigned u = __builtin_bit_cast(unsigned, f);
  u += 0x7fffu + ((u >> 16) & 1u);          // round-to-nearest-even
  return (unsigned short)(u >> 16);
}

__device__ __forceinline__ f32x4 mfma16(short8 a, short8 b, f32x4 c) {
  return __builtin_amdgcn_mfma_f32_16x16x32_bf16(
      __builtin_bit_cast(bf16x8, a), __builtin_bit_cast(bf16x8, b), c, 0, 0, 0);
}

// i8 MFMA, K=64: A 16 i8/lane (4 VGPR), B 16 i8/lane, C/D 4 i32.
__device__ __forceinline__ int4v mfma_i8(int4v a, int4v b, int4v c) {
  return __builtin_amdgcn_mfma_i32_16x16x64_i8(a, b, c, 0, 0, 0);
}

__device__ __forceinline__ short8 pack8v(f32x4 lo, f32x4 hi) {
  short8 r;
#pragma unroll
  for (int i = 0; i < 4; ++i) {
    r[i]     = (short)f2bf(lo[i]);
    r[i + 4] = (short)f2bf(hi[i]);
  }
  return r;
}

__device__ __forceinline__ short8 pack8(const float* __restrict__ p) {
  return pack8v(*reinterpret_cast<const f32x4*>(p),
                *reinterpret_cast<const f32x4*>(p + 4));
}

// LDS-only barrier: drain DS ops, sync; global stores/loads stay in flight.
__device__ __forceinline__ void step_barrier() {
  asm volatile("s_waitcnt lgkmcnt(0)" ::: "memory");
  __builtin_amdgcn_s_barrier();
  asm volatile("" ::: "memory");
}

// One block per batch. 512 threads = 8 waves (2/SIMD).
// Wave w owns hidden cols j in [w*32, w*32+32) as 2 j-tiles.
// h2h via i8 K=64 MFMA: A = broadcast h_q (i8), B = per-row-scaled Wh_q (i8),
// exact i32 accumulate, fp32 dequant. h_q lives in a 256B LDS chunk buffer
// [kt][lg][e] (k = kt*64 + lg*16 + e), double-buffered.
__global__ __launch_bounds__(512, 2)
void rnn_fused(const float* __restrict__ x,  const float* __restrict__ Wi,
               const float* __restrict__ bi, const float* __restrict__ Wh,
               const float* __restrict__ bh, const float* __restrict__ Wo,
               const float* __restrict__ bo, const float* __restrict__ h0,
               float* __restrict__ dout)
{
  const int b   = blockIdx.x;
  const int tid = threadIdx.x;
  const int w   = tid >> 6;   // wave 0..7
  const int l   = tid & 63;   // lane
  const int lg  = l >> 4;     // 16-lane group
  const int ll  = l & 15;     // index within tile

  __shared__ __align__(16) signed char    hq[2][256];       // i8 h, chunk layout
  __shared__ __align__(16) unsigned short rnnwin[16 * NH];  // 8 KB bf16 ring
  __shared__ __align__(16) float          xi_lds[NH][20];   // [j][t(16)+pad4]

  float* outp = dout;                              // [B,T,O]
  float* hidp = dout + (size_t)NB * NT * NO;       // [B,H]
  float* rnnp = hidp + (size_t)NB * NH;            // [B,T,H]

  const f32x4 cz = {0.f, 0.f, 0.f, 0.f};
  const int4v iz = {0, 0, 0, 0};

  // ---- Wh -> i8 B-fragments with per-row scale: lane holds col n=ll (row j),
  //      k = kt*64 + lg*16 + e ----
  int4v whq[2][4];
  float dq[2];
#pragma unroll
  for (int jt = 0; jt < 2; ++jt) {
    const int j = w * 32 + jt * 16 + ll;
    const float* wr = Wh + (size_t)j * NH;
    float m = 0.f;
#pragma unroll
    for (int kt = 0; kt < 4; ++kt)
#pragma unroll
      for (int e4 = 0; e4 < 4; ++e4) {
        f32x4 v = *reinterpret_cast<const f32x4*>(wr + kt * 64 + lg * 16 + e4 * 4);
#pragma unroll
        for (int i = 0; i < 4; ++i) m = fmaxf(m, fabsf(v[i]));
      }
    m = fmaxf(m, __shfl_xor(m, 16));
    m = fmaxf(m, __shfl_xor(m, 32));
    const float inv = (m > 0.f) ? 127.f / m : 0.f;
    dq[jt] = m / (127.f * 127.f);
#pragma unroll
    for (int kt = 0; kt < 4; ++kt) {
      unsigned u[4] = {0u, 0u, 0u, 0u};
#pragma unroll
      for (int e = 0; e < 16; ++e) {
        const float v = wr[kt * 64 + lg * 16 + e] * inv;
        int q = (int)(v + (v >= 0.f ? 0.5f : -0.5f));
        q = q > 127 ? 127 : (q < -127 ? -127 : q);
        u[e >> 2] |= ((unsigned)(q & 255)) << (8 * (e & 3));
      }
      int4v t; t[0] = (int)u[0]; t[1] = (int)u[1]; t[2] = (int)u[2]; t[3] = (int)u[3];
      whq[jt][kt] = t;
    }
  }

  // ---- bf16 i2h and out-proj weights (window-amortized paths) ----
  short8 wif[2][2];
#pragma unroll
  for (int jt = 0; jt < 2; ++jt) {
    const int j = w * 32 + jt * 16 + ll;
#pragma unroll
    for (int kx = 0; kx < 2; ++kx)
      wif[jt][kx] = pack8(Wi + (size_t)j * NI + kx * 32 + lg * 8);
  }
  short8 woA[8];
#pragma unroll
  for (int kt = 0; kt < 8; ++kt)
    woA[kt] = pack8(Wo + (size_t)ll * NH + kt * 32 + lg * 8);

  float breg[2];
  breg[0] = bi[w * 32 + ll]      + bh[w * 32 + ll];
  breg[1] = bi[w * 32 + 16 + ll] + bh[w * 32 + 16 + ll];
  const float bout = bo[ll];

  float h_reg0 = h0[w * 32 + ll];
  float h_reg1 = h0[w * 32 + 16 + ll];

  // writer lanes (lg<2): own j = w*32 + lg*16 + ll
  const int  jw   = w * 32 + lg * 16 + ll;
  const int  widx = ((jw >> 6) << 6) | (((jw >> 4) & 3) << 4) | (jw & 15);
  const bool wr_act = (lg < 2);

  // ---- init hq[0] from h0 ----
  if (tid < 256) {
    const int jj = tid;
    const int wi2 = ((jj >> 6) << 6) | (((jj >> 4) & 3) << 4) | (jj & 15);
    float hv = fminf(fmaxf(h0[jj], -1.f), 1.f);
    hq[0][wi2] = (signed char)(int)(hv * 127.f + (hv >= 0.f ? 0.5f : -0.5f));
  }

  // ---- x prefetch (one window ahead): lane row ll, 16 f32 ----
  const float* xrow = x + (size_t)b * NT * NI + (size_t)ll * NI + lg * 8;
  f32x4 xpre[4];
  xpre[0] = *reinterpret_cast<const f32x4*>(xrow);
  xpre[1] = *reinterpret_cast<const f32x4*>(xrow + 4);
  xpre[2] = *reinterpret_cast<const f32x4*>(xrow + 32);
  xpre[3] = *reinterpret_cast<const f32x4*>(xrow + 36);

  __syncthreads();

  const int j0 = w * 32 + ll;        // jt=0 row
  const int j1 = w * 32 + 16 + ll;   // jt=1 row

  auto outproj = [&](int tbase) {    // out[tbase-16 .. tbase-1] from rnnwin
    f32x4 oacc = cz;
#pragma unroll
    for (int kt = 0; kt < 8; ++kt) {
      const char* ap = (const char*)rnnwin + ll * 512 +
                       ((kt * 64 + lg * 16) ^ (ll << 4));
      short8 af = *reinterpret_cast<const short8*>(ap);
      oacc = mfma16(af, woA[kt], oacc);
    }
#pragma unroll
    for (int r = 0; r < 4; ++r) {
      const int tp = lg * 4 + r;
      outp[((size_t)b * NT + tbase - 16 + tp) * NO + ll] = oacc[r] + bout;
    }
  };

#pragma unroll 1
  for (int t0 = 0; t0 < NT; t0 += 16) {
    // ---- window boundary ----
    if (t0 > 0 && w == 0) outproj(t0);
    {
      short8 xf0 = pack8v(xpre[0], xpre[1]);
      short8 xf1 = pack8v(xpre[2], xpre[3]);
#pragma unroll
      for (int jt = 0; jt < 2; ++jt) {
        f32x4 acc = mfma16(xf0, wif[jt][0], cz);
        acc = mfma16(xf1, wif[jt][1], acc);
        const int j = w * 32 + jt * 16 + ll;
        *(f32x4*)&xi_lds[j][lg * 4] = acc;   // rows r -> t = lg*4 + r
      }
    }
    if (t0 + 16 < NT) {
      const float* xp = x + (size_t)b * NT * NI + (size_t)(t0 + 16 + ll) * NI + lg * 8;
      xpre[0] = *reinterpret_cast<const f32x4*>(xp);
      xpre[1] = *reinterpret_cast<const f32x4*>(xp + 4);
      xpre[2] = *reinterpret_cast<const f32x4*>(xp + 32);
      xpre[3] = *reinterpret_cast<const f32x4*>(xp + 36);
    }
    step_barrier();

#pragma unroll 1
    for (int q4 = 0; q4 < 4; ++q4) {
      const int tb = t0 + q4 * 4;
      f32x4 xiA = *(const f32x4*)&xi_lds[j0][q4 * 4];
      f32x4 xiB = *(const f32x4*)&xi_lds[j1][q4 * 4];

#define STEP(TT, SUB)                                                          \
      {                                                                        \
        const int t    = (TT);                                                 \
        const int trow = t & 15;                                               \
        const int p    = t & 1;                                                \
        int4v ha[4];                                                           \
        _Pragma("unroll")                                                      \
        for (int kt = 0; kt < 4; ++kt)                                         \
          ha[kt] = *(const int4v*)&hq[p][kt * 64 + lg * 16];                   \
        int4v acc0 = mfma_i8(ha[0], whq[0][0], iz);                            \
        int4v acc1 = mfma_i8(ha[0], whq[1][0], iz);                            \
        _Pragma("unroll")                                                      \
        for (int kt = 1; kt < 4; ++kt) {                                       \
          acc0 = mfma_i8(ha[kt], whq[0][kt], acc0);                            \
          acc1 = mfma_i8(ha[kt], whq[1][kt], acc1);                            \
        }                                                                      \
        const float a0 = fminf(fmaxf(                                          \
            (float)acc0[0] * dq[0] + h_reg0 + xiA[SUB] + breg[0], 0.f), 1.f);  \
        const float a1 = fminf(fmaxf(                                          \
            (float)acc1[0] * dq[1] + h_reg1 + xiB[SUB] + breg[1], 0.f), 1.f);  \
        h_reg0 = a0; h_reg1 = a1;                                              \
        if (wr_act) {                                                          \
          const float aw = lg ? a1 : a0;                                       \
          hq[p ^ 1][widx] = (signed char)(int)(aw * 127.f + 0.5f);             \
          const int byte = trow * 512 + ((2 * jw) ^ (trow << 4));              \
          rnnwin[byte >> 1] = f2bf(aw);                                        \
          rnnp[((size_t)b * NT + t) * NH + jw] = aw;                           \
        }                                                                      \
        step_barrier();                                                        \
      }

      STEP(tb + 0, 0)
      STEP(tb + 1, 1)
      STEP(tb + 2, 2)
      STEP(tb + 3, 3)
#undef STEP
    }
  }

  // ---- epilogue: final window out-proj + hidden ----
  if (w == 0) outproj(NT);
  if (wr_act) {
    const float aw = lg ? h_reg1 : h_reg0;
    hidp[(size_t)b * NH + jw] = aw;
  }
}

extern "C" void kernel_launch(void* const* d_in, const int* in_sizes, int n_in,
                              void* d_out, int out_size, void* d_ws, size_t ws_size,
                              hipStream_t stream) {
  const float* x  = (const float*)d_in[0];
  const float* Wi = (const float*)d_in[1];
  const float* bi = (const float*)d_in[2];
  const float* Wh = (const float*)d_in[3];
  const float* bh = (const float*)d_in[4];
  const float* Wo = (const float*)d_in[5];
  const float* bo = (const float*)d_in[6];
  const float* h0 = (const float*)d_in[7];
  rnn_fused<<<dim3(NB), dim3(512), 0, stream>>>(x, Wi, bi, Wh, bh, Wo, bo, h0,
                                                (float*)d_out);
}